// Round 1
// baseline (1058.603 us; speedup 1.0000x reference)
//
#include <hip/hip_runtime.h>

#define N_TOK 325
#define DKK 32
#define NSLICE 384                    // B*H*T = 4*8*12
#define SLICE_ELEMS (N_TOK*DKK)       // 10400
#define TOT (NSLICE*SLICE_ELEMS)      // 3,993,600 per tensor
#define NGROUP 8                      // 32-lane groups per 256-thread block
#define RPG 4                         // rows per group
#define CHUNK (NGROUP*RPG)            // 32 rows per chunk
#define NCHUNKS ((N_TOK + CHUNK - 1)/CHUNK)  // 11
#define VP 33                         // V row pitch (floats), +1 pad: bank = (m+d)%32
#define SP 328                        // S row pitch (floats), 16B-aligned rows
#define SCALE 0.17677669529663687f    // 1/sqrt(32)

// One block per (slice, variant). K staged dj-major (float4-friendly,
// conflict-free b128: dword addr = 4*(dj*325+m), m = lane+32k consecutive).
// V staged row-major pitch 33 (scalar reads conflict-free).
// Scores: 4-row register tile per 32-lane group; softmax distributed in
// registers via shfl_xor butterfly; P -> LDS; PV with broadcast float4 P reads.
__global__ __launch_bounds__(256, 1)
void attn4_kernel(const float* __restrict__ Qf, const float* __restrict__ Kf,
                  const float* __restrict__ Vf, const float* __restrict__ Qs,
                  const float* __restrict__ Ks, const float* __restrict__ Vs,
                  const float* __restrict__ Kj, const float* __restrict__ Vfp,
                  float* __restrict__ out)
{
    __shared__ float K4[SLICE_ELEMS];     // [(dj*325 + m)*4 + comp], dj=d>>2
    __shared__ float Vl[N_TOK * VP];
    __shared__ float Sl[CHUNK * SP];
    __shared__ float Ql[CHUNK * DKK];

    const int tid = threadIdx.x;
    const int bid = blockIdx.x;
    const int var = bid & 3;
    const int bt  = bid >> 2;             // 0..383
    const size_t base = (size_t)bt * SLICE_ELEMS;

    const float* qp; const float* kp; const float* vp;
    if (var == 0)      { qp = Qf; kp = Kf; vp = Vf; }
    else if (var == 1) { qp = Kf; kp = Qs; vp = Vf; }   // K = FlowSpeed(Qs)
    else if (var == 2) { qp = Ks; kp = Qf; vp = Vs; }
    else               { qp = Qs; kp = Ks; vp = Vs; }
    float* op = out + (size_t)var * TOT + base;

    // ---- stage K (dj-major) and V (row-major, padded) ----
    for (int idx = tid; idx < SLICE_ELEMS; idx += 256) {
        const int m = idx >> 5, d = idx & 31;
        float kv = kp[base + idx];
        if (var == 1) {
            const float kj = Kj[m], vf = Vfp[m];
            kv = kj * (kv - kv * kv / (vf + 1e-5f));
        }
        K4[((d >> 2) * N_TOK + m) * 4 + (d & 3)] = kv;
        Vl[m * VP + d] = vp[base + idx];
    }
    __syncthreads();

    const int g    = tid >> 5;   // group 0..7
    const int lane = tid & 31;

    for (int c = 0; c < NCHUNKS; ++c) {
        __syncthreads();  // protect Ql reuse across chunks
        // ---- stage Q chunk (rows clamped for safety on the tail) ----
        for (int idx = tid; idx < CHUNK * DKK; idx += 256) {
            const int r = idx >> 5, d = idx & 31;
            int row = c * CHUNK + r; if (row > N_TOK - 1) row = N_TOK - 1;
            Ql[idx] = qp[base + (size_t)row * DKK + d];
        }
        __syncthreads();

        // ---- scores: s[rr][k], cols m = lane + 32k ----
        float s[RPG][11];
        #pragma unroll
        for (int rr = 0; rr < RPG; ++rr)
            #pragma unroll
            for (int k = 0; k < 11; ++k) s[rr][k] = 0.f;

        #pragma unroll
        for (int dc = 0; dc < 4; ++dc) {
            float4 qa[RPG], qb[RPG];
            #pragma unroll
            for (int rr = 0; rr < RPG; ++rr) {
                const float* qrow = &Ql[(g * RPG + rr) * DKK + dc * 8];
                qa[rr] = *(const float4*)qrow;
                qb[rr] = *(const float4*)(qrow + 4);
            }
            #pragma unroll
            for (int k = 0; k < 11; ++k) {
                const int m = lane + 32 * k;
                if (m < N_TOK) {
                    const float4 ka = *(const float4*)&K4[((dc * 2    ) * N_TOK + m) * 4];
                    const float4 kb = *(const float4*)&K4[((dc * 2 + 1) * N_TOK + m) * 4];
                    #pragma unroll
                    for (int rr = 0; rr < RPG; ++rr) {
                        s[rr][k] += qa[rr].x * ka.x + qa[rr].y * ka.y
                                  + qa[rr].z * ka.z + qa[rr].w * ka.w
                                  + qb[rr].x * kb.x + qb[rr].y * kb.y
                                  + qb[rr].z * kb.z + qb[rr].w * kb.w;
                    }
                }
            }
        }

        // ---- softmax (distributed over 32-lane group) ----
        float inv[RPG];
        #pragma unroll
        for (int rr = 0; rr < RPG; ++rr) {
            float mv = -1e30f;
            #pragma unroll
            for (int k = 0; k < 11; ++k) {
                const int m = lane + 32 * k;
                if (m < N_TOK) { s[rr][k] *= SCALE; mv = fmaxf(mv, s[rr][k]); }
            }
            #pragma unroll
            for (int off = 16; off >= 1; off >>= 1) mv = fmaxf(mv, __shfl_xor(mv, off));
            float sv = 0.f;
            #pragma unroll
            for (int k = 0; k < 11; ++k) {
                const int m = lane + 32 * k;
                if (m < N_TOK) {
                    const float e = __expf(s[rr][k] - mv);
                    Sl[(g * RPG + rr) * SP + m] = e;
                    sv += e;
                }
            }
            #pragma unroll
            for (int off = 16; off >= 1; off >>= 1) sv += __shfl_xor(sv, off);
            inv[rr] = 1.0f / sv;
        }
        __syncthreads();  // conservative: order Sl writes vs PV reads

        // ---- PV: acc[rr] over d = lane ----
        float acc[RPG] = {0.f, 0.f, 0.f, 0.f};
        #pragma unroll 3
        for (int m4 = 0; m4 < 81; ++m4) {   // covers m = 0..323
            float4 p4[RPG];
            #pragma unroll
            for (int rr = 0; rr < RPG; ++rr)
                p4[rr] = *(const float4*)&Sl[(g * RPG + rr) * SP + m4 * 4];
            const float* pf = reinterpret_cast<const float*>(p4);
            #pragma unroll
            for (int j = 0; j < 4; ++j) {
                const float vv = Vl[(m4 * 4 + j) * VP + lane];
                #pragma unroll
                for (int rr = 0; rr < RPG; ++rr)
                    acc[rr] += pf[rr * 4 + j] * vv;
            }
        }
        {   // tail m = 324
            const float vv = Vl[324 * VP + lane];
            #pragma unroll
            for (int rr = 0; rr < RPG; ++rr)
                acc[rr] += Sl[(g * RPG + rr) * SP + 324] * vv;
        }

        // ---- write ----
        #pragma unroll
        for (int rr = 0; rr < RPG; ++rr) {
            const int row = c * CHUNK + g * RPG + rr;
            if (row < N_TOK) op[(size_t)row * DKK + lane] = acc[rr] * inv[rr];
        }
    }
}

extern "C" void kernel_launch(void* const* d_in, const int* in_sizes, int n_in,
                              void* d_out, int out_size, void* d_ws, size_t ws_size,
                              hipStream_t stream) {
    const float* Qf  = (const float*)d_in[0];
    const float* Kf  = (const float*)d_in[1];
    const float* Vf  = (const float*)d_in[2];
    const float* Qs  = (const float*)d_in[3];
    const float* Ks  = (const float*)d_in[4];
    const float* Vs  = (const float*)d_in[5];
    const float* Kj  = (const float*)d_in[6];
    const float* Vfp = (const float*)d_in[7];
    float* out = (float*)d_out;

    dim3 grid(NSLICE * 4);
    dim3 block(256);
    attn4_kernel<<<grid, block, 0, stream>>>(Qf, Kf, Vf, Qs, Ks, Vs, Kj, Vfp, out);
}

// Round 3
// 140.419 us; speedup vs baseline: 7.5389x; 7.5389x over previous
//
#include <hip/hip_runtime.h>
#include <hip/hip_bf16.h>

typedef float f32x4 __attribute__((ext_vector_type(4)));
typedef short short8 __attribute__((ext_vector_type(8)));

#define NT    325
#define DKK   32
#define NSL   384                 // B*H*T
#define SLICE (NT*DKK)            // 10400
#define TOTE  (NSL*SLICE)         // per-output-tensor elements
#define NKT   21                  // ceil(325/16)
#define PADV  352                 // 11*32, padded m for PV
#define SCALE 0.17677669529663687f

__device__ __forceinline__ unsigned bfu(float f) {
    __hip_bfloat16 h = __float2bfloat16(f);
    return (unsigned)__builtin_bit_cast(unsigned short, h);
}
__device__ __forceinline__ unsigned pk2(float lo, float hi) {
    return bfu(lo) | (bfu(hi) << 16);
}
// split x,y into bf16 hi pair (returned) and bf16 lo pair (written)
__device__ __forceinline__ unsigned pk2_split(float x, float y, unsigned& lopk) {
    const __hip_bfloat16 hx = __float2bfloat16(x);
    const __hip_bfloat16 hy = __float2bfloat16(y);
    const float rx = x - __bfloat162float(hx);
    const float ry = y - __bfloat162float(hy);
    lopk = bfu(rx) | (bfu(ry) << 16);
    return (unsigned)__builtin_bit_cast(unsigned short, hx)
         | ((unsigned)__builtin_bit_cast(unsigned short, hy) << 16);
}

// One block = one (slice, variant). 4 waves; wave w handles q-tiles w, w+4, ...
// Scores: S^T tile = mfma(A=K-frag, B=Q-frag) -> lane holds S[q=lane&15][m=kt*16+4g+r]
// Variant 1 (K = FlowSpeed(Qs), values up to ~1e3) uses 3-term bf16-split MFMA
// for fp32-like score precision: Kh*Ql + Kl*Qh + Kh*Qh.
// Softmax: in-register, reduce across lanes ^16, ^32.
// PV: A-frag assembled from P via 8 shfl + 4 sel per 32-m step; B = Vt (transposed LDS).
__global__ __launch_bounds__(256, 2)
void attn4_mfma(const float* __restrict__ Qf, const float* __restrict__ Kf,
                const float* __restrict__ Vf, const float* __restrict__ Qs,
                const float* __restrict__ Ks, const float* __restrict__ Vs,
                const float* __restrict__ Kj, const float* __restrict__ Vfp,
                float* __restrict__ out)
{
    __shared__ __align__(16) unsigned short Kb[336 * DKK];   // [m][d] bf16 hi, rows 325..335 stale (masked)
    __shared__ __align__(16) unsigned short Kl[336 * DKK];   // [m][d] bf16 lo (var==1 only)
    __shared__ __align__(16) unsigned short Vt[DKK * PADV];  // [d][m] bf16, m>=325 zeroed

    const int tid = threadIdx.x;
    const int bid = blockIdx.x;
    const int var = bid & 3;
    const int bt  = bid >> 2;
    const size_t base = (size_t)bt * SLICE;

    const float *qp, *kp, *vp;
    if      (var == 0) { qp = Qf; kp = Kf; vp = Vf; }
    else if (var == 1) { qp = Kf; kp = Qs; vp = Vf; }   // K = FlowSpeed(Qs)
    else if (var == 2) { qp = Ks; kp = Qf; vp = Vs; }
    else               { qp = Qs; kp = Ks; vp = Vs; }
    float* op = out + (size_t)var * TOTE + base;

    // ---- stage K -> Kb (bf16 hi) [+ Kl lo for var 1], 8 elems/thread ----
    for (int i8 = tid; i8 < SLICE / 8; i8 += 256) {
        const int idx = i8 * 8;
        const int m   = idx >> 5;
        const float* s = kp + base + idx;
        float4 a = *(const float4*)s;
        float4 b = *(const float4*)(s + 4);
        if (var == 1) {
            const float kj = Kj[m];
            const float rv = 1.0f / (Vfp[m] + 1e-5f);
            a.x = kj * (a.x - a.x * a.x * rv);
            a.y = kj * (a.y - a.y * a.y * rv);
            a.z = kj * (a.z - a.z * a.z * rv);
            a.w = kj * (a.w - a.w * a.w * rv);
            b.x = kj * (b.x - b.x * b.x * rv);
            b.y = kj * (b.y - b.y * b.y * rv);
            b.z = kj * (b.z - b.z * b.z * rv);
            b.w = kj * (b.w - b.w * b.w * rv);
            uint4 hw, lw;
            hw.x = pk2_split(a.x, a.y, lw.x);
            hw.y = pk2_split(a.z, a.w, lw.y);
            hw.z = pk2_split(b.x, b.y, lw.z);
            hw.w = pk2_split(b.z, b.w, lw.w);
            *(uint4*)&Kb[idx] = hw;
            *(uint4*)&Kl[idx] = lw;
        } else {
            uint4 pkv;
            pkv.x = pk2(a.x, a.y); pkv.y = pk2(a.z, a.w);
            pkv.z = pk2(b.x, b.y); pkv.w = pk2(b.z, b.w);
            *(uint4*)&Kb[idx] = pkv;
        }
    }

    // ---- stage V -> Vt (bf16, transposed, zero-padded to m=352) ----
    {
        const int dd = tid >> 3;            // 0..31
        for (int m8 = (tid & 7); m8 < PADV / 8; m8 += 8) {
            const int mb = m8 * 8;
            float v[8];
            #pragma unroll
            for (int i = 0; i < 8; ++i) {
                const int m = mb + i;
                v[i] = (m < NT) ? vp[base + (size_t)m * DKK + dd] : 0.0f;
            }
            uint4 pkv;
            pkv.x = pk2(v[0], v[1]); pkv.y = pk2(v[2], v[3]);
            pkv.z = pk2(v[4], v[5]); pkv.w = pk2(v[6], v[7]);
            *(uint4*)&Vt[dd * PADV + mb] = pkv;
        }
    }
    __syncthreads();

    const int lane = tid & 63;
    const int wv   = tid >> 6;
    const int c    = lane & 15;
    const int g    = lane >> 4;
    const int src0 = c | ((lane & 16) << 1);   // c + 32*(g&1)
    const int src1 = src0 + 16;
    const bool ghi = (g >= 2);
    const f32x4 zero = {0.f, 0.f, 0.f, 0.f};

    for (int qt = wv; qt < NKT; qt += 4) {
        // Q B-frag direct from global (coalesced), scale folded into bf16 cvt
        int qrow = qt * 16 + c;
        if (qrow > NT - 1) qrow = NT - 1;
        const float* qsrc = qp + base + (size_t)qrow * DKK + g * 8;
        const float4 qa = *(const float4*)qsrc;
        const float4 qb = *(const float4*)(qsrc + 4);
        uint4 qwh, qwl;
        qwh.x = pk2_split(qa.x * SCALE, qa.y * SCALE, qwl.x);
        qwh.y = pk2_split(qa.z * SCALE, qa.w * SCALE, qwl.y);
        qwh.z = pk2_split(qb.x * SCALE, qb.y * SCALE, qwl.z);
        qwh.w = pk2_split(qb.z * SCALE, qb.w * SCALE, qwl.w);
        const short8 qh = __builtin_bit_cast(short8, qwh);
        const short8 ql = __builtin_bit_cast(short8, qwl);

        // ---- scores: 21 independent k-tiles ----
        f32x4 acc[NKT];
        if (var != 1) {
            #pragma unroll
            for (int kt = 0; kt < NKT; ++kt) {
                const short8 kfrag = *(const short8*)&Kb[(kt * 16 + c) * DKK + g * 8];
                acc[kt] = __builtin_amdgcn_mfma_f32_16x16x32_bf16(kfrag, qh, zero, 0, 0, 0);
            }
        } else {
            #pragma unroll
            for (int kt = 0; kt < NKT; ++kt) {
                const short8 kh = *(const short8*)&Kb[(kt * 16 + c) * DKK + g * 8];
                const short8 kl = *(const short8*)&Kl[(kt * 16 + c) * DKK + g * 8];
                f32x4 t = __builtin_amdgcn_mfma_f32_16x16x32_bf16(kh, ql, zero, 0, 0, 0);
                t = __builtin_amdgcn_mfma_f32_16x16x32_bf16(kl, qh, t, 0, 0, 0);
                acc[kt] = __builtin_amdgcn_mfma_f32_16x16x32_bf16(kh, qh, t, 0, 0, 0);
            }
        }

        // mask m >= 325 (tile 20: m = 320 + 4g + r)
        #pragma unroll
        for (int r = 0; r < 4; ++r)
            acc[20][r] = (4 * g + r > 4) ? -1e30f : acc[20][r];

        // ---- softmax over m (q = c, copies at lanes ^16, ^32) ----
        float mv = -1e30f;
        #pragma unroll
        for (int kt = 0; kt < NKT; ++kt)
            #pragma unroll
            for (int r = 0; r < 4; ++r) mv = fmaxf(mv, acc[kt][r]);
        mv = fmaxf(mv, __shfl_xor(mv, 16));
        mv = fmaxf(mv, __shfl_xor(mv, 32));

        float sum = 0.f;
        #pragma unroll
        for (int kt = 0; kt < NKT; ++kt)
            #pragma unroll
            for (int r = 0; r < 4; ++r) {
                const float e = __expf(acc[kt][r] - mv);
                acc[kt][r] = e;
                sum += e;
            }
        sum += __shfl_xor(sum, 16);
        sum += __shfl_xor(sum, 32);
        const float inv = 1.0f / sum;

        // ---- pack P to bf16 pairs: P2[kt][p] = P[q=c][m=16kt+4g+2p..+1] ----
        unsigned P2[NKT][2];
        #pragma unroll
        for (int kt = 0; kt < NKT; ++kt) {
            P2[kt][0] = pk2(acc[kt][0], acc[kt][1]);
            P2[kt][1] = pk2(acc[kt][2], acc[kt][3]);
        }

        // ---- PV: O[q][d] = P * V, 11 m-steps of 32 ----
        f32x4 o0 = zero, o1 = zero;
        #pragma unroll
        for (int ks = 0; ks < 10; ++ks) {
            const unsigned x0 = __shfl(P2[2 * ks][0], src0);
            const unsigned x1 = __shfl(P2[2 * ks][1], src0);
            const unsigned x2 = __shfl(P2[2 * ks][0], src1);
            const unsigned x3 = __shfl(P2[2 * ks][1], src1);
            const unsigned y0 = __shfl(P2[2 * ks + 1][0], src0);
            const unsigned y1 = __shfl(P2[2 * ks + 1][1], src0);
            const unsigned y2 = __shfl(P2[2 * ks + 1][0], src1);
            const unsigned y3 = __shfl(P2[2 * ks + 1][1], src1);
            uint4 w;
            w.x = ghi ? y0 : x0; w.y = ghi ? y1 : x1;
            w.z = ghi ? y2 : x2; w.w = ghi ? y3 : x3;
            const short8 afrag = __builtin_bit_cast(short8, w);
            const short8 v0 = *(const short8*)&Vt[ c       * PADV + ks * 32 + g * 8];
            const short8 v1 = *(const short8*)&Vt[(c + 16) * PADV + ks * 32 + g * 8];
            o0 = __builtin_amdgcn_mfma_f32_16x16x32_bf16(afrag, v0, o0, 0, 0, 0);
            o1 = __builtin_amdgcn_mfma_f32_16x16x32_bf16(afrag, v1, o1, 0, 0, 0);
        }
        {   // ks = 10: m = 320..351; g>=2 supplies zeros (kt 21 doesn't exist)
            const unsigned x0 = __shfl(P2[20][0], src0);
            const unsigned x1 = __shfl(P2[20][1], src0);
            const unsigned x2 = __shfl(P2[20][0], src1);
            const unsigned x3 = __shfl(P2[20][1], src1);
            uint4 w;
            w.x = ghi ? 0u : x0; w.y = ghi ? 0u : x1;
            w.z = ghi ? 0u : x2; w.w = ghi ? 0u : x3;
            const short8 afrag = __builtin_bit_cast(short8, w);
            const short8 v0 = *(const short8*)&Vt[ c       * PADV + 320 + g * 8];
            const short8 v1 = *(const short8*)&Vt[(c + 16) * PADV + 320 + g * 8];
            o0 = __builtin_amdgcn_mfma_f32_16x16x32_bf16(afrag, v0, o0, 0, 0, 0);
            o1 = __builtin_amdgcn_mfma_f32_16x16x32_bf16(afrag, v1, o1, 0, 0, 0);
        }

        // ---- normalize (inv lives at lane with c == row-in-tile) and store ----
        #pragma unroll
        for (int r = 0; r < 4; ++r) {
            const int row = qt * 16 + 4 * g + r;
            const float iv = __shfl(inv, 4 * g + r);
            if (row < NT) {
                op[(size_t)row * DKK + c]      = o0[r] * iv;
                op[(size_t)row * DKK + c + 16] = o1[r] * iv;
            }
        }
    }
}

extern "C" void kernel_launch(void* const* d_in, const int* in_sizes, int n_in,
                              void* d_out, int out_size, void* d_ws, size_t ws_size,
                              hipStream_t stream) {
    const float* Qf  = (const float*)d_in[0];
    const float* Kf  = (const float*)d_in[1];
    const float* Vf  = (const float*)d_in[2];
    const float* Qs  = (const float*)d_in[3];
    const float* Ks  = (const float*)d_in[4];
    const float* Vs  = (const float*)d_in[5];
    const float* Kj  = (const float*)d_in[6];
    const float* Vfp = (const float*)d_in[7];
    float* out = (float*)d_out;

    attn4_mfma<<<dim3(NSL * 4), dim3(256), 0, stream>>>(Qf, Kf, Vf, Qs, Ks, Vs, Kj, Vfp, out);
}